// Round 10
// baseline (77.609 us; speedup 1.0000x reference)
//
#include <hip/hip_runtime.h>

// Cost volume: corr[b, dyi*9+dxi, y, x] = sum_c f1[b,c,y,x] * f2[b,c,y+dyi-4,x+dxi-4]
// (OOB f2 = 0). B=4, C=256, H=W=96, patch 9x9.
//
// Round 10 = round 9 with the pack-prepass indexing bug fixed.
//  R9 bug: pack decomposed q over 96x * 8 channel-groups (should be 32) and
//  launched 2304 blocks (should be 9216) -> only channels 0..63 packed, rest
//  of ws stayed 0xAA poison -> absmax 70.8. MFMA path never tested on valid
//  data.
//
//  Structure (unchanged from R9):
//  - Pack: f32 [b][c][y][x] -> f16 [b][y][x][c] (channel-major), both tensors.
//  - Main: banded Gram via mfma_f32_16x16x32_f16. Fragments are direct
//    contiguous 16B global loads (lane: x = l&15, c = (l>>4)*8 + ks*32; m97
//    gemm_bt pattern, zero LDS). Wave-task (b, y, m-tile, dy-triplet):
//    A-frags loaded once, reused over 3 dy x 2 n-tiles (n0 = m0-8, m0+8).
//  - C/D layout (m89/m91): row m = (lane>>4)*4+reg, col n = lane&15.
//    dx = x'-x+4; disjoint predicates write every output exactly once
//    (zeros for OOB included) -> no memset, deterministic.
//  - 2304 main blocks x 192 thr, bijective XCD swizzle (2304 = 8*288).

typedef _Float16 f16x8 __attribute__((ext_vector_type(8)));
typedef float f32x4 __attribute__((ext_vector_type(4)));

#define NB 4
#define NC 256
#define NH 96
#define NW 96
#define NP 9
#define PLANE (NH * NW)                       // 9216
#define TENS (NB * NH * NW * NC)              // 9,437,184 f16 per tensor
#define WS_NEED (2ull * (unsigned long long)TENS * 2ull)  // 37,748,736 B
#define TPT (TENS / 8)                        // pack threads per tensor: 1,179,648
#define PACK_BLK (2 * TPT / 256)              // 9216 blocks
#define MAIN_BLK 2304                         // 4b * 96y * 6mt
#define LPAD 37                               // fallback kernel LDS pad

// ---------- prepass: f32 [b][c][y][x] -> f16 [b][y][x][c] --------------------
__global__ __launch_bounds__(256) void pack_t(const float* __restrict__ f1,
                                              const float* __restrict__ f2,
                                              _Float16* __restrict__ ws)
{
    const int e   = blockIdx.x * 256 + threadIdx.x;   // 0 .. 2,359,295
    const int t   = e / TPT;                          // tensor 0/1
    const int r   = e % TPT;                          // 0 .. 1,179,647
    const int row = r / (NW * 32);                    // b*96 + y   (384)
    const int q   = r % (NW * 32);                    // 3072
    const int x   = q % NW;                           // coalesced read dim
    const int cg  = q / NW;                           // 8-channel group, 0..31
    const int b   = row / NH;
    const int y   = row % NH;

    const float* s  = t ? f2 : f1;
    const float* sp = s + ((size_t)(b * NC + cg * 8) * NH + y) * NW + x;
    f16x8 o;
#pragma unroll
    for (int j = 0; j < 8; ++j) o[j] = (_Float16)sp[(size_t)j * PLANE];
    *(f16x8*)(ws + (size_t)t * TENS + ((size_t)row * NW + x) * NC + cg * 8) = o;
}

// ---------- main: MFMA banded Gram -------------------------------------------
__global__ __launch_bounds__(192) void costvol_mfma(const _Float16* __restrict__ ws,
                                                    float* __restrict__ out)
{
    const _Float16* f1p = ws;
    const _Float16* f2p = ws + (size_t)TENS;

    const int bid = blockIdx.x;
    const int swz = (bid & 7) * (MAIN_BLK / 8) + (bid >> 3);
    const int mt  = swz % 6;                      // m-tile fastest (L2 reuse)
    const int y   = (swz / 6) % 96;
    const int b   = swz / 576;

    const int w    = threadIdx.x >> 6;            // wave 0..2 = dy-triplet
    const int lane = threadIdx.x & 63;
    const int lr   = lane & 15;                   // frag row (x / x') index
    const int lg   = lane >> 4;                   // k-group
    const int m0   = mt * 16;

    // A fragments: K = 256 in 8 steps of 32; channel = ks*32 + lg*8 + j
    const _Float16* pa = f1p + ((size_t)(b * 96 + y) * 96 + (m0 + lr)) * NC + lg * 8;
    f16x8 a[8];
#pragma unroll
    for (int ks = 0; ks < 8; ++ks) a[ks] = *(const f16x8*)(pa + ks * 32);

    const int n0a = m0 - 8 + lr;                  // x' for n-tile 0 (may be <0)
    const int n0b = m0 + 8 + lr;                  // x' for n-tile 1 (may be >=96)
    const bool inA = (n0a >= 0);
    const bool inB = (n0b < 96);
    const f16x8 bz = {};

#pragma unroll
    for (int i = 0; i < 3; ++i) {
        const int dy = w * 3 + i;
        const int y2 = y + dy - 4;
        f32x4 acc0 = {0.f, 0.f, 0.f, 0.f};
        f32x4 acc1 = {0.f, 0.f, 0.f, 0.f};

        if (y2 >= 0 && y2 < 96) {
            const _Float16* pb  = f2p + ((size_t)(b * 96 + y2) * 96) * NC;
            const _Float16* pba = pb + (size_t)n0a * NC + lg * 8;
            const _Float16* pbb = pb + (size_t)n0b * NC + lg * 8;
#pragma unroll
            for (int ks = 0; ks < 8; ++ks) {
                f16x8 b0 = bz, b1 = bz;
                if (inA) b0 = *(const f16x8*)(pba + ks * 32);
                if (inB) b1 = *(const f16x8*)(pbb + ks * 32);
                acc0 = __builtin_amdgcn_mfma_f32_16x16x32_f16(a[ks], b0, acc0, 0, 0, 0);
                acc1 = __builtin_amdgcn_mfma_f32_16x16x32_f16(a[ks], b1, acc1, 0, 0, 0);
            }
        }

        // writeout: D row m = m0 + lg*4 + reg (A row), col n = lr (B col)
        float* ob = out + ((size_t)(b * 81 + dy * 9) * PLANE) + y * 96;
#pragma unroll
        for (int reg = 0; reg < 4; ++reg) {
            const int mrow = lg * 4 + reg;
            const int m    = m0 + mrow;
            const int dx0  = lr - mrow - 4;       // tile0: x' = m0-8+lr
            const int dx1  = dx0 + 16;            // tile1: x' = m0+8+lr
            if (dx0 >= 0 && dx0 <= 8) ob[(size_t)dx0 * PLANE + m] = acc0[reg];
            if (dx1 >= 0 && dx1 <= 8) ob[(size_t)dx1 * PLANE + m] = acc1[reg];
        }
    }
}

// ---------- fallback: round-2 f32 kernel (if ws too small) -------------------
__global__ __launch_bounds__(256) void costvol_f32(const float* __restrict__ f1,
                                                   const float* __restrict__ f2,
                                                   float* __restrict__ out)
{
    __shared__ float lds[2 * 64 * LPAD];
    const int bid = blockIdx.x;
    const int swz = (bid & 7) * (1296 / 8) + (bid >> 3);
    const int dyi = swz % NP;
    const int g   = swz / NP;
    const int w    = threadIdx.x >> 6;
    const int lane = threadIdx.x & 63;
    const int chk = g * 64 + lane;
    const int b   = chk / (NH * 24);
    const int rem = chk - b * (NH * 24);
    const int y   = rem / 24;
    const int x0  = (rem - y * 24) * 4;
    const int y2  = y + dyi - 4;

    float acc[NP][4];
#pragma unroll
    for (int i = 0; i < NP; ++i)
#pragma unroll
        for (int j = 0; j < 4; ++j) acc[i][j] = 0.f;

    if (y2 >= 0 && y2 < NH) {
        const float* p1 = f1 + ((size_t)(b * NC + w * 64) * NH + y) * NW + x0;
        const float* p2 = f2 + ((size_t)(b * NC + w * 64) * NH + y2) * NW + x0;
        const bool hasL = (x0 >= 4);
        const bool hasR = (x0 <= NW - 8);
#pragma unroll 4
        for (int c = 0; c < 64; ++c) {
            const float4 av = *(const float4*)p1;
            const float4 Lv = hasL ? *(const float4*)(p2 - 4) : make_float4(0.f, 0.f, 0.f, 0.f);
            const float4 Mv = *(const float4*)(p2);
            const float4 Rv = hasR ? *(const float4*)(p2 + 4) : make_float4(0.f, 0.f, 0.f, 0.f);
            const float wv[12] = {Lv.x, Lv.y, Lv.z, Lv.w, Mv.x, Mv.y, Mv.z, Mv.w,
                                  Rv.x, Rv.y, Rv.z, Rv.w};
            const float aa[4] = {av.x, av.y, av.z, av.w};
#pragma unroll
            for (int dxi = 0; dxi < NP; ++dxi)
#pragma unroll
                for (int j = 0; j < 4; ++j) acc[dxi][j] += aa[j] * wv[dxi + j];
            p1 += PLANE;
            p2 += PLANE;
        }
    }

    float* reg0 = &lds[0 * 64 * LPAD + lane * LPAD];
    float* reg1 = &lds[1 * 64 * LPAD + lane * LPAD];
    if (w >= 2) {
        float* dst = (w == 2) ? reg0 : reg1;
#pragma unroll
        for (int dxi = 0; dxi < NP; ++dxi)
#pragma unroll
            for (int j = 0; j < 4; ++j) dst[dxi * 4 + j] = acc[dxi][j];
    }
    __syncthreads();
    if (w < 2) {
        const float* src = (w == 0) ? reg0 : reg1;
#pragma unroll
        for (int dxi = 0; dxi < NP; ++dxi)
#pragma unroll
            for (int j = 0; j < 4; ++j) acc[dxi][j] += src[dxi * 4 + j];
    }
    __syncthreads();
    if (w == 1) {
#pragma unroll
        for (int dxi = 0; dxi < NP; ++dxi)
#pragma unroll
            for (int j = 0; j < 4; ++j) reg0[dxi * 4 + j] = acc[dxi][j];
    }
    __syncthreads();
    if (w == 0) {
#pragma unroll
        for (int dxi = 0; dxi < NP; ++dxi)
#pragma unroll
            for (int j = 0; j < 4; ++j) acc[dxi][j] += reg0[dxi * 4 + j];
        float* ob = out + ((size_t)(b * 81 + dyi * 9) * NH + y) * NW + x0;
#pragma unroll
        for (int dxi = 0; dxi < NP; ++dxi) {
            *(float4*)ob = make_float4(acc[dxi][0], acc[dxi][1], acc[dxi][2], acc[dxi][3]);
            ob += PLANE;
        }
    }
}

extern "C" void kernel_launch(void* const* d_in, const int* in_sizes, int n_in,
                              void* d_out, int out_size, void* d_ws, size_t ws_size,
                              hipStream_t stream) {
    const float* f1 = (const float*)d_in[0];
    const float* f2 = (const float*)d_in[1];
    float* out = (float*)d_out;
    if (ws_size >= WS_NEED) {
        _Float16* ws = (_Float16*)d_ws;
        pack_t<<<dim3(PACK_BLK, 1, 1), dim3(256, 1, 1), 0, stream>>>(f1, f2, ws);
        costvol_mfma<<<dim3(MAIN_BLK, 1, 1), dim3(192, 1, 1), 0, stream>>>(ws, out);
    } else {
        costvol_f32<<<dim3(1296, 1, 1), dim3(256, 1, 1), 0, stream>>>(f1, f2, out);
    }
}

// Round 11
// 44.970 us; speedup vs baseline: 1.7258x; 1.7258x over previous
//
#include <hip/hip_runtime.h>

// Cost volume: corr[b, dyi*9+dxi, y, x] = sum_c f1[b,c,y,x] * f2[b,c,y+dyi-4,x+dxi-4]
// (OOB f2 = 0). B=4, C=256, H=W=96, patch 9x9.
//
// Round 11 = round 10 compute core + two data-movement fixes:
//  (1) ws layout [b][y][cg][x][8c] (f16): pack writes are now full-line
//      coalesced (lane = consecutive x -> contiguous 16B each); pack reads
//      unchanged (coalesced). Main fragment loads: 4x256B runs/instr, full
//      lines, same data per lane as R10 (c = ks*32 + lg*8 + j).
//  (2) main writeout via LDS: stage 81x16 cells (each written exactly once
//      by disjoint dx0/dx1 predicates; OOB-y2 zeros included), one barrier,
//      then block-cooperative float4 stores -- each (dy,dx) row is a full
//      64B line, vs 24 scattered scalar stores/wave in R10.

typedef _Float16 f16x8 __attribute__((ext_vector_type(8)));
typedef float f32x4 __attribute__((ext_vector_type(4)));

#define NB 4
#define NC 256
#define NH 96
#define NW 96
#define NP 9
#define PLANE (NH * NW)                       // 9216
#define TENS (NB * NH * NW * NC)              // 9,437,184 f16 per tensor
#define WS_NEED (2ull * (unsigned long long)TENS * 2ull)  // 37,748,736 B
#define TPT (TENS / 8)                        // 1,179,648 pack threads/tensor
#define PACK_BLK (2 * TPT / 256)              // 9216
#define MAIN_BLK 2304                         // 4b * 96y * 6mt
#define CGSTR (NW * 8)                        // 768 f16 per cg-plane
#define ROWSTR (32 * CGSTR)                   // 24576 f16 per (b,y) row
#define LPAD 37                               // fallback kernel pad

// ---------- prepass: f32 [b][c][y][x] -> f16 [b][y][cg][x][8] ---------------
__global__ __launch_bounds__(256) void pack_t(const float* __restrict__ f1,
                                              const float* __restrict__ f2,
                                              _Float16* __restrict__ ws)
{
    const int e   = blockIdx.x * 256 + threadIdx.x;   // 0 .. 2,359,295
    const int t   = e / TPT;                          // tensor 0/1
    const int r   = e % TPT;
    const int row = r / (NW * 32);                    // b*96 + y   (384)
    const int q   = r % (NW * 32);
    const int x   = q % NW;                           // lane-fastest
    const int cg  = q / NW;                           // 0..31
    const int b   = row / NH;
    const int y   = row % NH;

    const float* s  = t ? f2 : f1;
    const float* sp = s + ((size_t)(b * NC + cg * 8) * NH + y) * NW + x;
    f16x8 o;
#pragma unroll
    for (int j = 0; j < 8; ++j) o[j] = (_Float16)sp[(size_t)j * PLANE];
    // write addr: consecutive lanes (x) -> contiguous 16B -> full lines
    *(f16x8*)(ws + (size_t)t * TENS + ((size_t)row * 32 + cg) * CGSTR + (size_t)x * 8) = o;
}

// ---------- main: MFMA banded Gram ------------------------------------------
__global__ __launch_bounds__(192) void costvol_mfma(const _Float16* __restrict__ ws,
                                                    float* __restrict__ out)
{
    __shared__ float lds[81][20];                 // stride 20: f4-aligned, <=2-way

    const _Float16* f1p = ws;
    const _Float16* f2p = ws + (size_t)TENS;

    const int bid = blockIdx.x;
    const int swz = (bid & 7) * (MAIN_BLK / 8) + (bid >> 3);
    const int mt  = swz % 6;
    const int y   = (swz / 6) % 96;
    const int b   = swz / 576;

    const int w    = threadIdx.x >> 6;            // wave 0..2 = dy-triplet
    const int lane = threadIdx.x & 63;
    const int lr   = lane & 15;
    const int lg   = lane >> 4;
    const int m0   = mt * 16;

    // A frags: c = ks*32 + lg*8 + j  ->  cg = ks*4 + lg
    const _Float16* pa = f1p + ((size_t)(b * 96 + y) * 32 + lg) * CGSTR + (size_t)(m0 + lr) * 8;
    f16x8 a[8];
#pragma unroll
    for (int ks = 0; ks < 8; ++ks) a[ks] = *(const f16x8*)(pa + (size_t)ks * 4 * CGSTR);

    const int n0a = m0 - 8 + lr;                  // x' tile 0 (may be <0)
    const int n0b = m0 + 8 + lr;                  // x' tile 1 (may be >=96)
    const bool inA = (n0a >= 0);
    const bool inB = (n0b < 96);
    const f16x8 bz = {};

#pragma unroll
    for (int i = 0; i < 3; ++i) {
        const int dy = w * 3 + i;
        const int y2 = y + dy - 4;
        f32x4 acc0 = {0.f, 0.f, 0.f, 0.f};
        f32x4 acc1 = {0.f, 0.f, 0.f, 0.f};

        if (y2 >= 0 && y2 < 96) {
            const _Float16* base = f2p + (size_t)(b * 96 + y2) * ROWSTR + (size_t)lg * CGSTR;
            const _Float16* pba  = base + (ptrdiff_t)n0a * 8;
            const _Float16* pbb  = base + (ptrdiff_t)n0b * 8;
#pragma unroll
            for (int ks = 0; ks < 8; ++ks) {
                f16x8 b0 = bz, b1 = bz;
                if (inA) b0 = *(const f16x8*)(pba + (size_t)ks * 4 * CGSTR);
                if (inB) b1 = *(const f16x8*)(pbb + (size_t)ks * 4 * CGSTR);
                acc0 = __builtin_amdgcn_mfma_f32_16x16x32_f16(a[ks], b0, acc0, 0, 0, 0);
                acc1 = __builtin_amdgcn_mfma_f32_16x16x32_f16(a[ks], b1, acc1, 0, 0, 0);
            }
        }

        // stage to LDS: D row m = m0+lg*4+reg, col n = lr; disjoint dx0/dx1
        // predicates cover every (dx in 0..8, mrow) exactly once.
#pragma unroll
        for (int reg = 0; reg < 4; ++reg) {
            const int mrow = lg * 4 + reg;
            const int dx0  = lr - mrow - 4;       // tile0: x' = m0-8+lr
            const int dx1  = dx0 + 16;            // tile1: x' = m0+8+lr
            if (dx0 >= 0 && dx0 <= 8) lds[dy * 9 + dx0][mrow] = acc0[reg];
            if (dx1 >= 0 && dx1 <= 8) lds[dy * 9 + dx1][mrow] = acc1[reg];
        }
    }

    __syncthreads();

    // coalesced writeout: row r = dy*9+dx -> 64B line; 324 float4s, 192 thr
    const int q = (threadIdx.x & 3) * 4;
#pragma unroll
    for (int r = threadIdx.x >> 2; r < 81; r += 48) {
        const float4 v = make_float4(lds[r][q], lds[r][q + 1],
                                     lds[r][q + 2], lds[r][q + 3]);
        *(float4*)(out + ((size_t)(b * 81 + r) * PLANE) + y * 96 + m0 + q) = v;
    }
}

// ---------- fallback: round-2 f32 kernel (if ws too small) ------------------
__global__ __launch_bounds__(256) void costvol_f32(const float* __restrict__ f1,
                                                   const float* __restrict__ f2,
                                                   float* __restrict__ out)
{
    __shared__ float lds[2 * 64 * LPAD];
    const int bid = blockIdx.x;
    const int swz = (bid & 7) * (1296 / 8) + (bid >> 3);
    const int dyi = swz % NP;
    const int g   = swz / NP;
    const int w    = threadIdx.x >> 6;
    const int lane = threadIdx.x & 63;
    const int chk = g * 64 + lane;
    const int b   = chk / (NH * 24);
    const int rem = chk - b * (NH * 24);
    const int y   = rem / 24;
    const int x0  = (rem - y * 24) * 4;
    const int y2  = y + dyi - 4;

    float acc[NP][4];
#pragma unroll
    for (int i = 0; i < NP; ++i)
#pragma unroll
        for (int j = 0; j < 4; ++j) acc[i][j] = 0.f;

    if (y2 >= 0 && y2 < NH) {
        const float* p1 = f1 + ((size_t)(b * NC + w * 64) * NH + y) * NW + x0;
        const float* p2 = f2 + ((size_t)(b * NC + w * 64) * NH + y2) * NW + x0;
        const bool hasL = (x0 >= 4);
        const bool hasR = (x0 <= NW - 8);
#pragma unroll 4
        for (int c = 0; c < 64; ++c) {
            const float4 av = *(const float4*)p1;
            const float4 Lv = hasL ? *(const float4*)(p2 - 4) : make_float4(0.f, 0.f, 0.f, 0.f);
            const float4 Mv = *(const float4*)(p2);
            const float4 Rv = hasR ? *(const float4*)(p2 + 4) : make_float4(0.f, 0.f, 0.f, 0.f);
            const float wv[12] = {Lv.x, Lv.y, Lv.z, Lv.w, Mv.x, Mv.y, Mv.z, Mv.w,
                                  Rv.x, Rv.y, Rv.z, Rv.w};
            const float aa[4] = {av.x, av.y, av.z, av.w};
#pragma unroll
            for (int dxi = 0; dxi < NP; ++dxi)
#pragma unroll
                for (int j = 0; j < 4; ++j) acc[dxi][j] += aa[j] * wv[dxi + j];
            p1 += PLANE;
            p2 += PLANE;
        }
    }

    float* reg0 = &lds[0 * 64 * LPAD + lane * LPAD];
    float* reg1 = &lds[1 * 64 * LPAD + lane * LPAD];
    if (w >= 2) {
        float* dst = (w == 2) ? reg0 : reg1;
#pragma unroll
        for (int dxi = 0; dxi < NP; ++dxi)
#pragma unroll
            for (int j = 0; j < 4; ++j) dst[dxi * 4 + j] = acc[dxi][j];
    }
    __syncthreads();
    if (w < 2) {
        const float* src = (w == 0) ? reg0 : reg1;
#pragma unroll
        for (int dxi = 0; dxi < NP; ++dxi)
#pragma unroll
            for (int j = 0; j < 4; ++j) acc[dxi][j] += src[dxi * 4 + j];
    }
    __syncthreads();
    if (w == 1) {
#pragma unroll
        for (int dxi = 0; dxi < NP; ++dxi)
#pragma unroll
            for (int j = 0; j < 4; ++j) reg0[dxi * 4 + j] = acc[dxi][j];
    }
    __syncthreads();
    if (w == 0) {
#pragma unroll
        for (int dxi = 0; dxi < NP; ++dxi)
#pragma unroll
            for (int j = 0; j < 4; ++j) acc[dxi][j] += reg0[dxi * 4 + j];
        float* ob = out + ((size_t)(b * 81 + dyi * 9) * NH + y) * NW + x0;
#pragma unroll
        for (int dxi = 0; dxi < NP; ++dxi) {
            *(float4*)ob = make_float4(acc[dxi][0], acc[dxi][1], acc[dxi][2], acc[dxi][3]);
            ob += PLANE;
        }
    }
}

extern "C" void kernel_launch(void* const* d_in, const int* in_sizes, int n_in,
                              void* d_out, int out_size, void* d_ws, size_t ws_size,
                              hipStream_t stream) {
    const float* f1 = (const float*)d_in[0];
    const float* f2 = (const float*)d_in[1];
    float* out = (float*)d_out;
    if (ws_size >= WS_NEED) {
        _Float16* ws = (_Float16*)d_ws;
        pack_t<<<dim3(PACK_BLK, 1, 1), dim3(256, 1, 1), 0, stream>>>(f1, f2, ws);
        costvol_mfma<<<dim3(MAIN_BLK, 1, 1), dim3(192, 1, 1), 0, stream>>>(ws, out);
    } else {
        costvol_f32<<<dim3(1296, 1, 1), dim3(256, 1, 1), 0, stream>>>(f1, f2, out);
    }
}

// Round 12
// 44.704 us; speedup vs baseline: 1.7361x; 1.0060x over previous
//
#include <hip/hip_runtime.h>

// Cost volume: corr[b, dyi*9+dxi, y, x] = sum_c f1[b,c,y,x] * f2[b,c,y+dyi-4,x+dxi-4]
// (OOB f2 = 0). B=4, C=256, H=W=96, patch 9x9.
//
// Round 12 = round 11 + two latency fixes:
//  (1) main: explicit B0[8]/B1[8] fragment arrays -- all 16 B-loads issued
//      BEFORE the 16 MFMAs. R10/R11 VGPR_Count=40 proved the compiler left
//      ~8 VGPRs for B (A frags = 32) and serialized load->wait->MFMA in
//      batches of ~2. #pragma unroll 1 on the dy loop pins one buffer set
//      (~120 VGPR -> 4 waves/SIMD, 16 loads in flight per wave).
//  (2) pack: x4-vectorized (8 float4 coalesced loads + 4 contiguous 16B
//      stores per thread, register transpose, static indexing), 2304 blocks.

typedef _Float16 f16x8 __attribute__((ext_vector_type(8)));
typedef float f32x4 __attribute__((ext_vector_type(4)));

#define NB 4
#define NC 256
#define NH 96
#define NW 96
#define NP 9
#define PLANE (NH * NW)                       // 9216
#define TENS (NB * NH * NW * NC)              // 9,437,184 f16 per tensor
#define WS_NEED (2ull * (unsigned long long)TENS * 2ull)  // 37,748,736 B
#define TPT4 (TENS / 32)                      // 294,912 pack threads/tensor
#define PACK_BLK (2 * TPT4 / 256)             // 2304
#define MAIN_BLK 2304                         // 4b * 96y * 6mt
#define CGSTR (NW * 8)                        // 768 f16 per cg-plane
#define ROWSTR (32 * CGSTR)                   // 24576 f16 per (b,y) row
#define LPAD 37                               // fallback kernel pad

// ---------- prepass: f32 [b][c][y][x] -> f16 [b][y][cg][x][8] ---------------
__global__ __launch_bounds__(256) void pack_t(const float* __restrict__ f1,
                                              const float* __restrict__ f2,
                                              _Float16* __restrict__ ws)
{
    const int e   = blockIdx.x * 256 + threadIdx.x;   // 0 .. 589,823
    const int t   = e / TPT4;                         // tensor 0/1
    const int r   = e % TPT4;
    const int row = r / 768;                          // b*96 + y   (384)
    const int q   = r % 768;
    const int cg  = q / 24;                           // 0..31
    const int x4  = q % 24;                           // lane-fastest (coalesced)
    const int b   = row / NH;
    const int y   = row % NH;

    const float* s  = t ? f2 : f1;
    const float* sp = s + ((size_t)(b * NC + cg * 8) * NH + y) * NW + x4 * 4;
    float vv[8][4];
#pragma unroll
    for (int j = 0; j < 8; ++j) {
        const float4 v = *(const float4*)(sp + (size_t)j * PLANE);
        vv[j][0] = v.x; vv[j][1] = v.y; vv[j][2] = v.z; vv[j][3] = v.w;
    }
    _Float16* dp = ws + (size_t)t * TENS + ((size_t)row * 32 + cg) * CGSTR
                 + (size_t)x4 * 32;                   // 4 x * 8 c = 64 B contig
#pragma unroll
    for (int xi = 0; xi < 4; ++xi) {
        f16x8 o;
#pragma unroll
        for (int j = 0; j < 8; ++j) o[j] = (_Float16)vv[j][xi];
        *(f16x8*)(dp + xi * 8) = o;
    }
}

// ---------- main: MFMA banded Gram ------------------------------------------
__global__ __launch_bounds__(192) void costvol_mfma(const _Float16* __restrict__ ws,
                                                    float* __restrict__ out)
{
    __shared__ float lds[81][20];

    const _Float16* f1p = ws;
    const _Float16* f2p = ws + (size_t)TENS;

    const int bid = blockIdx.x;
    const int swz = (bid & 7) * (MAIN_BLK / 8) + (bid >> 3);
    const int mt  = swz % 6;
    const int y   = (swz / 6) % 96;
    const int b   = swz / 576;

    const int w    = threadIdx.x >> 6;            // wave 0..2 = dy-triplet
    const int lane = threadIdx.x & 63;
    const int lr   = lane & 15;
    const int lg   = lane >> 4;
    const int m0   = mt * 16;

    // A frags: c = ks*32 + lg*8 + j  ->  cg = ks*4 + lg
    const _Float16* pa = f1p + ((size_t)(b * 96 + y) * 32 + lg) * CGSTR + (size_t)(m0 + lr) * 8;
    f16x8 a[8];
#pragma unroll
    for (int ks = 0; ks < 8; ++ks) a[ks] = *(const f16x8*)(pa + (size_t)ks * 4 * CGSTR);

    const int n0a = m0 - 8 + lr;                  // x' tile 0 (may be <0)
    const int n0b = m0 + 8 + lr;                  // x' tile 1 (may be >=96)
    const bool inA = (n0a >= 0);
    const bool inB = (n0b < 96);
    const f16x8 bz = {};

#pragma unroll 1
    for (int i = 0; i < 3; ++i) {
        const int dy = w * 3 + i;
        const int y2 = y + dy - 4;
        f32x4 acc0 = {0.f, 0.f, 0.f, 0.f};
        f32x4 acc1 = {0.f, 0.f, 0.f, 0.f};

        if (y2 >= 0 && y2 < 96) {
            const _Float16* base = f2p + (size_t)(b * 96 + y2) * ROWSTR + (size_t)lg * CGSTR;
            const _Float16* pba  = base + (ptrdiff_t)n0a * 8;
            const _Float16* pbb  = base + (ptrdiff_t)n0b * 8;
            f16x8 B0[8], B1[8];
#pragma unroll
            for (int ks = 0; ks < 8; ++ks) {      // issue ALL 16 loads first
                B0[ks] = inA ? *(const f16x8*)(pba + (size_t)ks * 4 * CGSTR) : bz;
                B1[ks] = inB ? *(const f16x8*)(pbb + (size_t)ks * 4 * CGSTR) : bz;
            }
#pragma unroll
            for (int ks = 0; ks < 8; ++ks) {      // then the MFMA chain
                acc0 = __builtin_amdgcn_mfma_f32_16x16x32_f16(a[ks], B0[ks], acc0, 0, 0, 0);
                acc1 = __builtin_amdgcn_mfma_f32_16x16x32_f16(a[ks], B1[ks], acc1, 0, 0, 0);
            }
        }

        // stage to LDS: D row m = m0+lg*4+reg, col n = lr; disjoint dx0/dx1
#pragma unroll
        for (int reg = 0; reg < 4; ++reg) {
            const int mrow = lg * 4 + reg;
            const int dx0  = lr - mrow - 4;       // tile0: x' = m0-8+lr
            const int dx1  = dx0 + 16;            // tile1: x' = m0+8+lr
            if (dx0 >= 0 && dx0 <= 8) lds[dy * 9 + dx0][mrow] = acc0[reg];
            if (dx1 >= 0 && dx1 <= 8) lds[dy * 9 + dx1][mrow] = acc1[reg];
        }
    }

    __syncthreads();

    // coalesced writeout: row r = dy*9+dx -> 64B line
    const int q = (threadIdx.x & 3) * 4;
#pragma unroll
    for (int r = threadIdx.x >> 2; r < 81; r += 48) {
        const float4 v = make_float4(lds[r][q], lds[r][q + 1],
                                     lds[r][q + 2], lds[r][q + 3]);
        *(float4*)(out + ((size_t)(b * 81 + r) * PLANE) + y * 96 + m0 + q) = v;
    }
}

// ---------- fallback: round-2 f32 kernel (if ws too small) ------------------
__global__ __launch_bounds__(256) void costvol_f32(const float* __restrict__ f1,
                                                   const float* __restrict__ f2,
                                                   float* __restrict__ out)
{
    __shared__ float lds[2 * 64 * LPAD];
    const int bid = blockIdx.x;
    const int swz = (bid & 7) * (1296 / 8) + (bid >> 3);
    const int dyi = swz % NP;
    const int g   = swz / NP;
    const int w    = threadIdx.x >> 6;
    const int lane = threadIdx.x & 63;
    const int chk = g * 64 + lane;
    const int b   = chk / (NH * 24);
    const int rem = chk - b * (NH * 24);
    const int y   = rem / 24;
    const int x0  = (rem - y * 24) * 4;
    const int y2  = y + dyi - 4;

    float acc[NP][4];
#pragma unroll
    for (int i = 0; i < NP; ++i)
#pragma unroll
        for (int j = 0; j < 4; ++j) acc[i][j] = 0.f;

    if (y2 >= 0 && y2 < NH) {
        const float* p1 = f1 + ((size_t)(b * NC + w * 64) * NH + y) * NW + x0;
        const float* p2 = f2 + ((size_t)(b * NC + w * 64) * NH + y2) * NW + x0;
        const bool hasL = (x0 >= 4);
        const bool hasR = (x0 <= NW - 8);
#pragma unroll 4
        for (int c = 0; c < 64; ++c) {
            const float4 av = *(const float4*)p1;
            const float4 Lv = hasL ? *(const float4*)(p2 - 4) : make_float4(0.f, 0.f, 0.f, 0.f);
            const float4 Mv = *(const float4*)(p2);
            const float4 Rv = hasR ? *(const float4*)(p2 + 4) : make_float4(0.f, 0.f, 0.f, 0.f);
            const float wv[12] = {Lv.x, Lv.y, Lv.z, Lv.w, Mv.x, Mv.y, Mv.z, Mv.w,
                                  Rv.x, Rv.y, Rv.z, Rv.w};
            const float aa[4] = {av.x, av.y, av.z, av.w};
#pragma unroll
            for (int dxi = 0; dxi < NP; ++dxi)
#pragma unroll
                for (int j = 0; j < 4; ++j) acc[dxi][j] += aa[j] * wv[dxi + j];
            p1 += PLANE;
            p2 += PLANE;
        }
    }

    float* reg0 = &lds[0 * 64 * LPAD + lane * LPAD];
    float* reg1 = &lds[1 * 64 * LPAD + lane * LPAD];
    if (w >= 2) {
        float* dst = (w == 2) ? reg0 : reg1;
#pragma unroll
        for (int dxi = 0; dxi < NP; ++dxi)
#pragma unroll
            for (int j = 0; j < 4; ++j) dst[dxi * 4 + j] = acc[dxi][j];
    }
    __syncthreads();
    if (w < 2) {
        const float* src = (w == 0) ? reg0 : reg1;
#pragma unroll
        for (int dxi = 0; dxi < NP; ++dxi)
#pragma unroll
            for (int j = 0; j < 4; ++j) acc[dxi][j] += src[dxi * 4 + j];
    }
    __syncthreads();
    if (w == 1) {
#pragma unroll
        for (int dxi = 0; dxi < NP; ++dxi)
#pragma unroll
            for (int j = 0; j < 4; ++j) reg0[dxi * 4 + j] = acc[dxi][j];
    }
    __syncthreads();
    if (w == 0) {
#pragma unroll
        for (int dxi = 0; dxi < NP; ++dxi)
#pragma unroll
            for (int j = 0; j < 4; ++j) acc[dxi][j] += reg0[dxi * 4 + j];
        float* ob = out + ((size_t)(b * 81 + dyi * 9) * NH + y) * NW + x0;
#pragma unroll
        for (int dxi = 0; dxi < NP; ++dxi) {
            *(float4*)ob = make_float4(acc[dxi][0], acc[dxi][1], acc[dxi][2], acc[dxi][3]);
            ob += PLANE;
        }
    }
}

extern "C" void kernel_launch(void* const* d_in, const int* in_sizes, int n_in,
                              void* d_out, int out_size, void* d_ws, size_t ws_size,
                              hipStream_t stream) {
    const float* f1 = (const float*)d_in[0];
    const float* f2 = (const float*)d_in[1];
    float* out = (float*)d_out;
    if (ws_size >= WS_NEED) {
        _Float16* ws = (_Float16*)d_ws;
        pack_t<<<dim3(PACK_BLK, 1, 1), dim3(256, 1, 1), 0, stream>>>(f1, f2, ws);
        costvol_mfma<<<dim3(MAIN_BLK, 1, 1), dim3(192, 1, 1), 0, stream>>>(ws, out);
    } else {
        costvol_f32<<<dim3(1296, 1, 1), dim3(256, 1, 1), 0, stream>>>(f1, f2, out);
    }
}

// Round 13
// 41.183 us; speedup vs baseline: 1.8845x; 1.0855x over previous
//
#include <hip/hip_runtime.h>

// Cost volume: corr[b, dyi*9+dxi, y, x] = sum_c f1[b,c,y,x] * f2[b,c,y+dyi-4,x+dxi-4]
// (OOB f2 = 0). B=4, C=256, H=W=96, patch 9x9.
//
// Round 13 = round 12 with the pack halved: only f2 is repacked.
//  Pack was ~18us (113 MB stream, both tensors). The A-fragment needs
//  f1[b, c, y, m0+lr] with 16 consecutive x per (c) -- loadable DIRECTLY
//  from the f32 layout as coalesced 64B lines (64 dword loads per wave,
//  once per block, converted to f16 in-register). Only f2 (the B operand,
//  channel-contiguous per lane) needs the channel-major transpose.
//  Pack traffic 113 -> 56.6 MB.
//  Main compute core, LDS writeout, swizzles unchanged (verified R10-R12).

typedef _Float16 f16x8 __attribute__((ext_vector_type(8)));
typedef float f32x4 __attribute__((ext_vector_type(4)));

#define NB 4
#define NC 256
#define NH 96
#define NW 96
#define NP 9
#define PLANE (NH * NW)                       // 9216
#define TENS (NB * NH * NW * NC)              // 9,437,184 f16 (f2 only)
#define WS_NEED ((unsigned long long)TENS * 2ull)  // 18,874,368 B
#define TPT4 (TENS / 32)                      // 294,912 pack threads
#define PACK_BLK (TPT4 / 256)                 // 1152
#define MAIN_BLK 2304                         // 4b * 96y * 6mt
#define CGSTR (NW * 8)                        // 768 f16 per cg-plane
#define ROWSTR (32 * CGSTR)                   // 24576 f16 per (b,y) row
#define LPAD 37                               // fallback kernel pad

// ---------- prepass: f2 f32 [b][c][y][x] -> f16 [b][y][cg][x][8] ------------
__global__ __launch_bounds__(256) void pack_f2(const float* __restrict__ f2,
                                               _Float16* __restrict__ ws)
{
    const int e   = blockIdx.x * 256 + threadIdx.x;   // 0 .. 294,911
    const int row = e / 768;                          // b*96 + y   (384)
    const int q   = e % 768;
    const int cg  = q / 24;                           // 0..31
    const int x4  = q % 24;                           // lane-fastest (coalesced)
    const int b   = row / NH;
    const int y   = row % NH;

    const float* sp = f2 + ((size_t)(b * NC + cg * 8) * NH + y) * NW + x4 * 4;
    float vv[8][4];
#pragma unroll
    for (int j = 0; j < 8; ++j) {
        const float4 v = *(const float4*)(sp + (size_t)j * PLANE);
        vv[j][0] = v.x; vv[j][1] = v.y; vv[j][2] = v.z; vv[j][3] = v.w;
    }
    _Float16* dp = ws + ((size_t)row * 32 + cg) * CGSTR + (size_t)x4 * 32;
#pragma unroll
    for (int xi = 0; xi < 4; ++xi) {
        f16x8 o;
#pragma unroll
        for (int j = 0; j < 8; ++j) o[j] = (_Float16)vv[j][xi];
        *(f16x8*)(dp + xi * 8) = o;
    }
}

// ---------- main: MFMA banded Gram ------------------------------------------
__global__ __launch_bounds__(192) void costvol_mfma(const float* __restrict__ f1,
                                                    const _Float16* __restrict__ f2p,
                                                    float* __restrict__ out)
{
    __shared__ float lds[81][20];

    const int bid = blockIdx.x;
    const int swz = (bid & 7) * (MAIN_BLK / 8) + (bid >> 3);
    const int mt  = swz % 6;
    const int y   = (swz / 6) % 96;
    const int b   = swz / 576;

    const int w    = threadIdx.x >> 6;            // wave 0..2 = dy-triplet
    const int lane = threadIdx.x & 63;
    const int lr   = lane & 15;
    const int lg   = lane >> 4;
    const int m0   = mt * 16;

    // A frags DIRECT from f32: c = lg*8 + ks*32 + j; 16 lanes (lr) share a
    // 64B line per (c). 64 dword loads + cvt, once per wave.
    const float* pa32 = f1 + ((size_t)(b * NC + lg * 8) * NH + y) * NW + (m0 + lr);
    f16x8 a[8];
#pragma unroll
    for (int ks = 0; ks < 8; ++ks) {
        f16x8 o;
#pragma unroll
        for (int j = 0; j < 8; ++j)
            o[j] = (_Float16)pa32[(size_t)(ks * 32 + j) * PLANE];
        a[ks] = o;
    }

    const int n0a = m0 - 8 + lr;                  // x' tile 0 (may be <0)
    const int n0b = m0 + 8 + lr;                  // x' tile 1 (may be >=96)
    const bool inA = (n0a >= 0);
    const bool inB = (n0b < 96);
    const f16x8 bz = {};

#pragma unroll 1
    for (int i = 0; i < 3; ++i) {
        const int dy = w * 3 + i;
        const int y2 = y + dy - 4;
        f32x4 acc0 = {0.f, 0.f, 0.f, 0.f};
        f32x4 acc1 = {0.f, 0.f, 0.f, 0.f};

        if (y2 >= 0 && y2 < 96) {
            const _Float16* base = f2p + (size_t)(b * 96 + y2) * ROWSTR + (size_t)lg * CGSTR;
            const _Float16* pba  = base + (ptrdiff_t)n0a * 8;
            const _Float16* pbb  = base + (ptrdiff_t)n0b * 8;
            f16x8 B0[8], B1[8];
#pragma unroll
            for (int ks = 0; ks < 8; ++ks) {      // issue all 16 loads first
                B0[ks] = inA ? *(const f16x8*)(pba + (size_t)ks * 4 * CGSTR) : bz;
                B1[ks] = inB ? *(const f16x8*)(pbb + (size_t)ks * 4 * CGSTR) : bz;
            }
#pragma unroll
            for (int ks = 0; ks < 8; ++ks) {
                acc0 = __builtin_amdgcn_mfma_f32_16x16x32_f16(a[ks], B0[ks], acc0, 0, 0, 0);
                acc1 = __builtin_amdgcn_mfma_f32_16x16x32_f16(a[ks], B1[ks], acc1, 0, 0, 0);
            }
        }

        // stage to LDS: D row m = m0+lg*4+reg, col n = lr; disjoint dx0/dx1
#pragma unroll
        for (int reg = 0; reg < 4; ++reg) {
            const int mrow = lg * 4 + reg;
            const int dx0  = lr - mrow - 4;       // tile0: x' = m0-8+lr
            const int dx1  = dx0 + 16;            // tile1: x' = m0+8+lr
            if (dx0 >= 0 && dx0 <= 8) lds[dy * 9 + dx0][mrow] = acc0[reg];
            if (dx1 >= 0 && dx1 <= 8) lds[dy * 9 + dx1][mrow] = acc1[reg];
        }
    }

    __syncthreads();

    // coalesced writeout: row r = dy*9+dx -> 64B line
    const int q = (threadIdx.x & 3) * 4;
#pragma unroll
    for (int r = threadIdx.x >> 2; r < 81; r += 48) {
        const float4 v = make_float4(lds[r][q], lds[r][q + 1],
                                     lds[r][q + 2], lds[r][q + 3]);
        *(float4*)(out + ((size_t)(b * 81 + r) * PLANE) + y * 96 + m0 + q) = v;
    }
}

// ---------- fallback: round-2 f32 kernel (if ws too small) ------------------
__global__ __launch_bounds__(256) void costvol_f32(const float* __restrict__ f1,
                                                   const float* __restrict__ f2,
                                                   float* __restrict__ out)
{
    __shared__ float lds[2 * 64 * LPAD];
    const int bid = blockIdx.x;
    const int swz = (bid & 7) * (1296 / 8) + (bid >> 3);
    const int dyi = swz % NP;
    const int g   = swz / NP;
    const int w    = threadIdx.x >> 6;
    const int lane = threadIdx.x & 63;
    const int chk = g * 64 + lane;
    const int b   = chk / (NH * 24);
    const int rem = chk - b * (NH * 24);
    const int y   = rem / 24;
    const int x0  = (rem - y * 24) * 4;
    const int y2  = y + dyi - 4;

    float acc[NP][4];
#pragma unroll
    for (int i = 0; i < NP; ++i)
#pragma unroll
        for (int j = 0; j < 4; ++j) acc[i][j] = 0.f;

    if (y2 >= 0 && y2 < NH) {
        const float* p1 = f1 + ((size_t)(b * NC + w * 64) * NH + y) * NW + x0;
        const float* p2 = f2 + ((size_t)(b * NC + w * 64) * NH + y2) * NW + x0;
        const bool hasL = (x0 >= 4);
        const bool hasR = (x0 <= NW - 8);
#pragma unroll 4
        for (int c = 0; c < 64; ++c) {
            const float4 av = *(const float4*)p1;
            const float4 Lv = hasL ? *(const float4*)(p2 - 4) : make_float4(0.f, 0.f, 0.f, 0.f);
            const float4 Mv = *(const float4*)(p2);
            const float4 Rv = hasR ? *(const float4*)(p2 + 4) : make_float4(0.f, 0.f, 0.f, 0.f);
            const float wv[12] = {Lv.x, Lv.y, Lv.z, Lv.w, Mv.x, Mv.y, Mv.z, Mv.w,
                                  Rv.x, Rv.y, Rv.z, Rv.w};
            const float aa[4] = {av.x, av.y, av.z, av.w};
#pragma unroll
            for (int dxi = 0; dxi < NP; ++dxi)
#pragma unroll
                for (int j = 0; j < 4; ++j) acc[dxi][j] += aa[j] * wv[dxi + j];
            p1 += PLANE;
            p2 += PLANE;
        }
    }

    float* reg0 = &lds[0 * 64 * LPAD + lane * LPAD];
    float* reg1 = &lds[1 * 64 * LPAD + lane * LPAD];
    if (w >= 2) {
        float* dst = (w == 2) ? reg0 : reg1;
#pragma unroll
        for (int dxi = 0; dxi < NP; ++dxi)
#pragma unroll
            for (int j = 0; j < 4; ++j) dst[dxi * 4 + j] = acc[dxi][j];
    }
    __syncthreads();
    if (w < 2) {
        const float* src = (w == 0) ? reg0 : reg1;
#pragma unroll
        for (int dxi = 0; dxi < NP; ++dxi)
#pragma unroll
            for (int j = 0; j < 4; ++j) acc[dxi][j] += src[dxi * 4 + j];
    }
    __syncthreads();
    if (w == 1) {
#pragma unroll
        for (int dxi = 0; dxi < NP; ++dxi)
#pragma unroll
            for (int j = 0; j < 4; ++j) reg0[dxi * 4 + j] = acc[dxi][j];
    }
    __syncthreads();
    if (w == 0) {
#pragma unroll
        for (int dxi = 0; dxi < NP; ++dxi)
#pragma unroll
            for (int j = 0; j < 4; ++j) acc[dxi][j] += reg0[dxi * 4 + j];
        float* ob = out + ((size_t)(b * 81 + dyi * 9) * NH + y) * NW + x0;
#pragma unroll
        for (int dxi = 0; dxi < NP; ++dxi) {
            *(float4*)ob = make_float4(acc[dxi][0], acc[dxi][1], acc[dxi][2], acc[dxi][3]);
            ob += PLANE;
        }
    }
}

extern "C" void kernel_launch(void* const* d_in, const int* in_sizes, int n_in,
                              void* d_out, int out_size, void* d_ws, size_t ws_size,
                              hipStream_t stream) {
    const float* f1 = (const float*)d_in[0];
    const float* f2 = (const float*)d_in[1];
    float* out = (float*)d_out;
    if (ws_size >= WS_NEED) {
        _Float16* ws = (_Float16*)d_ws;
        pack_f2<<<dim3(PACK_BLK, 1, 1), dim3(256, 1, 1), 0, stream>>>(f2, ws);
        costvol_mfma<<<dim3(MAIN_BLK, 1, 1), dim3(192, 1, 1), 0, stream>>>(f1, ws, out);
    } else {
        costvol_f32<<<dim3(1296, 1, 1), dim3(256, 1, 1), 0, stream>>>(f1, f2, out);
    }
}